// Round 8
// baseline (688.623 us; speedup 1.0000x reference)
//
#include <hip/hip_runtime.h>
#include <math.h>

#define IN_DIM 128
#define HID 64
#define HEADS 4
#define HH 256   // HEADS*HID
#define OUT_DIM 64
#define NEG_SLOPE 0.2f

typedef unsigned short ushort_t;
using bf16x8 = __attribute__((ext_vector_type(8))) short;
using f32x4  = __attribute__((ext_vector_type(4))) float;

__device__ __forceinline__ float elu_f(float x){ return x > 0.f ? x : (expf(x) - 1.f); }
__device__ __forceinline__ float lrelu_f(float x){ return fmaxf(x, NEG_SLOPE * x); }

__device__ __forceinline__ ushort_t f2bf(float x){
  unsigned u = __float_as_uint(x);
  unsigned r = (u + 0x7fffu + ((u >> 16) & 1u)) >> 16;
  return (ushort_t)r;
}
__device__ __forceinline__ float bf2f(ushort_t v){ return __uint_as_float(((unsigned)v) << 16); }

// ---- prep: bf16 weights in MFMA B layout + transposed proj weight + summed user bias
// Wt{0,1,2}[h][o][c] = lin[c][h*64+o]; Wot[o][k] = Wo[k][o]; Wpt[c][k] = Wp[k][c]
__global__ void prep_kernel(const float* __restrict__ L0, const float* __restrict__ L1,
                            const float* __restrict__ L2, const float* __restrict__ Wo,
                            const float* __restrict__ Wp,
                            const float* __restrict__ b0, const float* __restrict__ b1,
                            ushort_t* __restrict__ Wt0, ushort_t* __restrict__ Wt1,
                            ushort_t* __restrict__ Wt2, ushort_t* __restrict__ Wot,
                            ushort_t* __restrict__ Wpt, float* __restrict__ bsum){
  int g = blockIdx.x * 256 + threadIdx.x;
  if (g < 49152){
    int m = g >> 14;
    int i = g & 16383;
    int h = i >> 12, rem = i & 4095;
    int o = rem >> 6, c = rem & 63;
    const float* L = m == 0 ? L0 : (m == 1 ? L1 : L2);
    ushort_t* W = m == 0 ? Wt0 : (m == 1 ? Wt1 : Wt2);
    W[i] = f2bf(L[(size_t)c * HH + h * 64 + o]);
  } else if (g < 65536){
    int i = g - 49152;
    int o = i >> 8, k = i & 255;
    Wot[i] = f2bf(Wo[(size_t)k * OUT_DIM + o]);
  } else if (g < 73728){
    int i = g - 65536;             // Wpt: c = i>>7, k = i&127
    int c = i >> 7, k = i & 127;
    Wpt[i] = f2bf(Wp[(size_t)k * HID + c]);
  } else if (g < 73984){
    int i = g - 73728;
    bsum[i] = b0[i] + b1[i];
  }
}

// ---- proj via MFMA: h = x @ Wp + b, h stored bf16. 64 rows/block, 4 waves.
__global__ void proj_mfma(const float* __restrict__ xu, const float* __restrict__ xp,
                          const ushort_t* __restrict__ Wpt, const float* __restrict__ b,
                          ushort_t* __restrict__ hu, ushort_t* __restrict__ hp,
                          int n_user, int n_total){
  __shared__ ushort_t xs[64 * 128];   // 16 KB, byte ^= (row&7)<<4 swizzle
  int tid = threadIdx.x;
  int row0 = blockIdx.x * 64;
  #pragma unroll
  for (int p = 0; p < 4; ++p){
    int idx = (p * 256 + tid) * 8;          // element in [0, 8192)
    int r = idx >> 7, k = idx & 127;
    int gr = row0 + r;
    float4 v0 = make_float4(0,0,0,0), v1 = make_float4(0,0,0,0);
    if (gr < n_total){
      const float* src = (gr < n_user) ? (xu + (size_t)gr * IN_DIM + k)
                                       : (xp + (size_t)(gr - n_user) * IN_DIM + k);
      v0 = *(const float4*)src; v1 = *(const float4*)(src + 4);
    }
    bf16x8 bv;
    bv[0] = (short)f2bf(v0.x); bv[1] = (short)f2bf(v0.y);
    bv[2] = (short)f2bf(v0.z); bv[3] = (short)f2bf(v0.w);
    bv[4] = (short)f2bf(v1.x); bv[5] = (short)f2bf(v1.y);
    bv[6] = (short)f2bf(v1.z); bv[7] = (short)f2bf(v1.w);
    int byteoff = r * 256 + ((k * 2) ^ ((r & 7) << 4));
    *(bf16x8*)((char*)xs + byteoff) = bv;
  }
  __syncthreads();
  int w = tid >> 6, lane = tid & 63, l15 = lane & 15, kg = lane >> 4;
  int arow = w * 16 + l15;
  bf16x8 afrag[4];
  #pragma unroll
  for (int ks = 0; ks < 4; ++ks){
    int k = ks * 32 + kg * 8;
    int byteoff = arow * 256 + ((k * 2) ^ ((arow & 7) << 4));
    afrag[ks] = *(const bf16x8*)((const char*)xs + byteoff);
  }
  #pragma unroll
  for (int n16 = 0; n16 < 4; ++n16){
    f32x4 acc = {0.f, 0.f, 0.f, 0.f};
    const ushort_t* wp = Wpt + (n16 * 16 + l15) * 128;
    #pragma unroll
    for (int ks = 0; ks < 4; ++ks)
      acc = __builtin_amdgcn_mfma_f32_16x16x32_bf16(afrag[ks], *(const bf16x8*)(wp + ks * 32 + kg * 8), acc, 0, 0, 0);
    int col = n16 * 16 + l15;
    float bb = b[col];
    #pragma unroll
    for (int j = 0; j < 4; ++j){
      int row = row0 + w * 16 + kg * 4 + j;
      if (row < n_total){
        ushort_t hv = f2bf(acc[j] + bb);
        if (row < n_user) hu[(size_t)row * HID + col] = hv;
        else              hp[(size_t)(row - n_user) * HID + col] = hv;
      }
    }
  }
}

// ---- batched fold: 3 blocks; wbuf layout: [t*2+0]=w_s, [t*2+1]=w_d (each 256)
__global__ void fold3_kernel(const float* __restrict__ lin0, const float* __restrict__ as0, const float* __restrict__ ad0,
                             const float* __restrict__ lin1, const float* __restrict__ as1, const float* __restrict__ ad1,
                             const float* __restrict__ lin2, const float* __restrict__ as2, const float* __restrict__ ad2,
                             float* __restrict__ wbuf){
  int t = blockIdx.x;
  const float* lin = t == 0 ? lin0 : (t == 1 ? lin1 : lin2);
  const float* as  = t == 0 ? as0  : (t == 1 ? as1  : as2);
  const float* ad  = t == 0 ? ad0  : (t == 1 ? ad1  : ad2);
  int tid = threadIdx.x;
  int h = tid >> 6, k = tid & 63;
  float vs = 0.f, vd = 0.f;
  for (int c = 0; c < HID; ++c){
    float lv = lin[k * HH + h * HID + c];
    vs += lv * as[h * HID + c];
    vd += lv * ad[h * HID + c];
  }
  wbuf[(t * 2 + 0) * HH + tid] = vs;
  wbuf[(t * 2 + 1) * HH + tid] = vd;
}

// ---- batched node attention: 6 segments; h is bf16 now
__global__ void att6_kernel(const ushort_t* __restrict__ hu, const ushort_t* __restrict__ hp,
                            const float* __restrict__ wbuf, float* __restrict__ abuf,
                            int n_user, int n_post, int n_max){
  long gw = ((long)blockIdx.x * blockDim.x + threadIdx.x) >> 6;
  int lane = threadIdx.x & 63;
  int seg, node;
  long r = gw;
  int nu = n_user, np_ = n_post;
  if      (r < nu)            { seg = 0; node = (int)r; }
  else if ((r -= nu) < nu)    { seg = 1; node = (int)r; }
  else if ((r -= nu) < np_)   { seg = 2; node = (int)r; }
  else if ((r -= np_) < nu)   { seg = 3; node = (int)r; }
  else if ((r -= nu) < nu)    { seg = 4; node = (int)r; }
  else if ((r -= nu) < np_)   { seg = 5; node = (int)r; }
  else return;
  const ushort_t* h = (seg == 2 || seg == 5) ? hp : hu;
  const float* w = wbuf + seg * HH;
  float* outp = abuf + (size_t)seg * n_max * HEADS;
  float hv = bf2f(h[(size_t)node * HID + lane]);
  #pragma unroll
  for (int hh = 0; hh < HEADS; ++hh){
    float p = hv * w[hh * HID + lane];
    #pragma unroll
    for (int off = 32; off > 0; off >>= 1) p += __shfl_xor(p, off, 64);
    if (lane == 0) outp[(size_t)node * HEADS + hh] = p;
  }
}

// ======== batched CSR build over 3 types ========
__global__ void hist3_kernel(const int* __restrict__ d0, const int* __restrict__ d1,
                             const int* __restrict__ d2, int* __restrict__ deg3,
                             int E0, int E1, int E2, int b1_, int b2_){
  int e = blockIdx.x * blockDim.x + threadIdx.x;
  int ET = E0 + E1 + E2;
  if (e >= ET) return;
  int idx;
  if (e < E0)            idx = d0[e];
  else if (e < E0 + E1)  idx = b1_ + d1[e - E0];
  else                   idx = b2_ + d2[e - E0 - E1];
  atomicAdd(deg3 + idx, 1);
}

__global__ void scan1_kernel(const int* __restrict__ deg, int* __restrict__ offs,
                             int* __restrict__ bsum, int n){
  __shared__ int sm[256];
  int i = blockIdx.x * 256 + threadIdx.x;
  int v = (i < n) ? deg[i] : 0;
  sm[threadIdx.x] = v;
  __syncthreads();
  for (int off = 1; off < 256; off <<= 1){
    int t = (threadIdx.x >= off) ? sm[threadIdx.x - off] : 0;
    __syncthreads();
    sm[threadIdx.x] += t;
    __syncthreads();
  }
  if (i < n) offs[i] = sm[threadIdx.x] - v;
  if (threadIdx.x == 255) bsum[blockIdx.x] = sm[255];
}

__global__ void scan2_kernel(int* __restrict__ bsum, int nb){
  __shared__ int sm[1024];
  int v = (threadIdx.x < nb) ? bsum[threadIdx.x] : 0;
  sm[threadIdx.x] = v;
  __syncthreads();
  for (int off = 1; off < 1024; off <<= 1){
    int t = (threadIdx.x >= off) ? sm[threadIdx.x - off] : 0;
    __syncthreads();
    sm[threadIdx.x] += t;
    __syncthreads();
  }
  if (threadIdx.x < nb) bsum[threadIdx.x] = sm[threadIdx.x] - v;
}

__global__ void scan3_kernel(int* __restrict__ offs, int* __restrict__ cursor,
                             const int* __restrict__ bsum, int n){
  int i = blockIdx.x * 256 + threadIdx.x;
  if (i >= n) return;
  int o = offs[i] + bsum[blockIdx.x];
  offs[i] = o;
  cursor[i] = o;
}

__global__ void csrfill3_kernel(const int* __restrict__ s0, const int* __restrict__ d0,
                                const int* __restrict__ s1, const int* __restrict__ d1,
                                const int* __restrict__ s2, const int* __restrict__ d2,
                                int* __restrict__ cursor, int* __restrict__ csr_src,
                                int E0, int E1, int E2, int b1_, int b2_){
  int e = blockIdx.x * blockDim.x + threadIdx.x;
  int ET = E0 + E1 + E2;
  if (e >= ET) return;
  int sidx, didx;
  if (e < E0){ sidx = s0[e]; didx = d0[e]; }
  else if (e < E0 + E1){ int ee = e - E0; sidx = s1[ee]; didx = b1_ + d1[ee]; }
  else { int ee = e - E0 - E1; sidx = s2[ee]; didx = b2_ + d2[ee]; }
  int pos = atomicAdd(cursor + didx, 1);
  csr_src[pos] = sidx;
}

// ---- stats+alpha: thread per dst; alpha[e] = exp(lrelu(a_s+a_d)) / sum, CSR-ordered
__global__ void stats_alpha_kernel(const int* __restrict__ csr_src, const int* __restrict__ offs3,
                                   const int* __restrict__ deg3, const float* __restrict__ abuf,
                                   float4* __restrict__ alpha,
                                   int n_user, int n_post, int n_max){
  int gw = blockIdx.x * 256 + threadIdx.x;
  int n3 = 2 * n_user + n_post;
  if (gw >= n3) return;
  size_t astr = (size_t)n_max;   // float4 units
  const float4* as4; const float4* ad4; int dloc;
  const float4* ab = (const float4*)abuf;
  if (gw < n_user){ dloc = gw; as4 = ab; ad4 = ab + astr; }
  else if (gw < 2 * n_user){ dloc = gw - n_user; as4 = ab + 2 * astr; ad4 = ab + 3 * astr; }
  else { dloc = gw - 2 * n_user; as4 = ab + 4 * astr; ad4 = ab + 5 * astr; }
  int base = offs3[gw], n = deg3[gw];
  float4 ad = ad4[dloc];
  float s0 = 0.f, s1 = 0.f, s2 = 0.f, s3 = 0.f;
  for (int j = 0; j < n; ++j){
    float4 a = as4[csr_src[base + j]];
    s0 += __expf(lrelu_f(a.x + ad.x));
    s1 += __expf(lrelu_f(a.y + ad.y));
    s2 += __expf(lrelu_f(a.z + ad.z));
    s3 += __expf(lrelu_f(a.w + ad.w));
  }
  float i0 = 1.f / (s0 + 1e-16f), i1 = 1.f / (s1 + 1e-16f);
  float i2 = 1.f / (s2 + 1e-16f), i3 = 1.f / (s3 + 1e-16f);
  for (int j = 0; j < n; ++j){
    float4 a = as4[csr_src[base + j]];
    alpha[base + j] = make_float4(__expf(lrelu_f(a.x + ad.x)) * i0,
                                  __expf(lrelu_f(a.y + ad.y)) * i1,
                                  __expf(lrelu_f(a.z + ad.z)) * i2,
                                  __expf(lrelu_f(a.w + ad.w)) * i3);
  }
}

// ---- slim gather: wave per dst; pure weighted sum of bf16 h rows
__global__ void gather_slim(const int* __restrict__ csr_src, const int* __restrict__ offs3,
                            const int* __restrict__ deg3,
                            const ushort_t* __restrict__ hu, const ushort_t* __restrict__ hp,
                            const float4* __restrict__ alpha,
                            int n_user, int n_post,
                            ushort_t* __restrict__ aggA, ushort_t* __restrict__ aggB,
                            ushort_t* __restrict__ aggC){
  int gw = blockIdx.x * 4 + (threadIdx.x >> 6);
  int lane = threadIdx.x & 63;
  int n3 = 2 * n_user + n_post;
  if (gw >= n3) return;
  const ushort_t* h; ushort_t* agg; int dloc;
  if (gw < n_user){ dloc = gw; h = hu; agg = aggA; }
  else if (gw < 2 * n_user){ dloc = gw - n_user; h = hp; agg = aggB; }
  else { dloc = gw - 2 * n_user; h = hu; agg = aggC; }
  int base = offs3[gw], n = deg3[gw];
  float a0 = 0.f, a1 = 0.f, a2 = 0.f, a3 = 0.f;
  float hA = 0.f, hB = 0.f;
  if (n > 0) hA = bf2f(h[(size_t)csr_src[base] * HID + lane]);
  if (n > 1) hB = bf2f(h[(size_t)csr_src[base + 1] * HID + lane]);
  for (int j = 0; j < n; ++j){
    float hv = hA; hA = hB;
    if (j + 2 < n) hB = bf2f(h[(size_t)csr_src[base + j + 2] * HID + lane]);
    float4 al = alpha[base + j];
    a0 = fmaf(al.x, hv, a0); a1 = fmaf(al.y, hv, a1);
    a2 = fmaf(al.z, hv, a2); a3 = fmaf(al.w, hv, a3);
  }
  size_t o = (size_t)dloc * HH + lane;
  agg[o + 0 * HID] = f2bf(a0);
  agg[o + 1 * HID] = f2bf(a1);
  agg[o + 2 * HID] = f2bf(a2);
  agg[o + 3 * HID] = f2bf(a3);
}

// ---- user epilogue (MFMA): out_user = elu(aggA@L0 + aggB@L1 + bsum) @ Wo + bo
__global__ void user_epi_mfma(const ushort_t* __restrict__ aggA, const ushort_t* __restrict__ aggB,
                              const ushort_t* __restrict__ Wt0, const ushort_t* __restrict__ Wt1,
                              const ushort_t* __restrict__ Wot, const float* __restrict__ bsum,
                              const float* __restrict__ bo, float* __restrict__ out, int n){
  __shared__ ushort_t Tl[64 * 256];   // 32 KB, swizzled: byte ^= (row&7)<<4
  int tid = threadIdx.x;
  int w = tid >> 6, lane = tid & 63;
  int l15 = lane & 15, kg = lane >> 4;
  int row0 = blockIdx.x * 64 + w * 16;

  int ar = row0 + l15; if (ar > n - 1) ar = n - 1;
  #pragma unroll
  for (int h = 0; h < HEADS; ++h){
    const ushort_t* pa = aggA + (size_t)ar * HH + h * 64 + kg * 8;
    const ushort_t* pb = aggB + (size_t)ar * HH + h * 64 + kg * 8;
    bf16x8 aA0 = *(const bf16x8*)pa;
    bf16x8 aA1 = *(const bf16x8*)(pa + 32);
    bf16x8 aB0 = *(const bf16x8*)pb;
    bf16x8 aB1 = *(const bf16x8*)(pb + 32);
    #pragma unroll
    for (int n16 = 0; n16 < 4; ++n16){
      int o = n16 * 16 + l15;
      const ushort_t* w0 = Wt0 + h * 4096 + o * 64 + kg * 8;
      const ushort_t* w1 = Wt1 + h * 4096 + o * 64 + kg * 8;
      f32x4 acc = {0.f, 0.f, 0.f, 0.f};
      acc = __builtin_amdgcn_mfma_f32_16x16x32_bf16(aA0, *(const bf16x8*)w0, acc, 0, 0, 0);
      acc = __builtin_amdgcn_mfma_f32_16x16x32_bf16(aA1, *(const bf16x8*)(w0 + 32), acc, 0, 0, 0);
      acc = __builtin_amdgcn_mfma_f32_16x16x32_bf16(aB0, *(const bf16x8*)w1, acc, 0, 0, 0);
      acc = __builtin_amdgcn_mfma_f32_16x16x32_bf16(aB1, *(const bf16x8*)(w1 + 32), acc, 0, 0, 0);
      int col = h * 64 + n16 * 16 + l15;
      float bb = bsum[col];
      #pragma unroll
      for (int j = 0; j < 4; ++j){
        int rl = w * 16 + kg * 4 + j;
        float v = elu_f(acc[j] + bb);
        int byteoff = rl * 512 + ((col * 2) ^ ((rl & 7) << 4));
        Tl[byteoff >> 1] = f2bf(v);
      }
    }
  }
  __syncthreads();

  int rl = w * 16 + l15;
  #pragma unroll
  for (int nf = 0; nf < 4; ++nf){
    f32x4 acc = {0.f, 0.f, 0.f, 0.f};
    const ushort_t* wp = Wot + (nf * 16 + l15) * 256 + kg * 8;
    #pragma unroll
    for (int ks = 0; ks < 8; ++ks){
      int ab = rl * 512 + ((ks * 64 + kg * 16) ^ ((rl & 7) << 4));
      bf16x8 a = *(const bf16x8*)((const char*)Tl + ab);
      acc = __builtin_amdgcn_mfma_f32_16x16x32_bf16(a, *(const bf16x8*)(wp + ks * 32), acc, 0, 0, 0);
    }
    int colo = nf * 16 + l15;
    float bb = bo[colo];
    #pragma unroll
    for (int j = 0; j < 4; ++j){
      int row = blockIdx.x * 64 + w * 16 + kg * 4 + j;
      if (row < n) out[(size_t)row * OUT_DIM + colo] = acc[j] + bb;
    }
  }
}

// ---- post epilogue (MFMA): out_post = elu(aggC@L2 + b2)
__global__ void post_epi_mfma(const ushort_t* __restrict__ aggC, const ushort_t* __restrict__ Wt2,
                              const float* __restrict__ b2, float* __restrict__ out, int n){
  int tid = threadIdx.x;
  int w = tid >> 6, lane = tid & 63;
  int l15 = lane & 15, kg = lane >> 4;
  int row0 = blockIdx.x * 64 + w * 16;
  int ar = row0 + l15; if (ar > n - 1) ar = n - 1;
  #pragma unroll
  for (int h = 0; h < HEADS; ++h){
    const ushort_t* pa = aggC + (size_t)ar * HH + h * 64 + kg * 8;
    bf16x8 a0 = *(const bf16x8*)pa;
    bf16x8 a1 = *(const bf16x8*)(pa + 32);
    #pragma unroll
    for (int n16 = 0; n16 < 4; ++n16){
      int o = n16 * 16 + l15;
      const ushort_t* w2 = Wt2 + h * 4096 + o * 64 + kg * 8;
      f32x4 acc = {0.f, 0.f, 0.f, 0.f};
      acc = __builtin_amdgcn_mfma_f32_16x16x32_bf16(a0, *(const bf16x8*)w2, acc, 0, 0, 0);
      acc = __builtin_amdgcn_mfma_f32_16x16x32_bf16(a1, *(const bf16x8*)(w2 + 32), acc, 0, 0, 0);
      int col = h * 64 + n16 * 16 + l15;
      float bb = b2[col];
      #pragma unroll
      for (int j = 0; j < 4; ++j){
        int row = row0 + kg * 4 + j;
        if (row < n) out[(size_t)row * HH + col] = elu_f(acc[j] + bb);
      }
    }
  }
}

extern "C" void kernel_launch(void* const* d_in, const int* in_sizes, int n_in,
                              void* d_out, int out_size, void* d_ws, size_t ws_size,
                              hipStream_t stream){
  const float* xu = (const float*)d_in[0];
  const float* xp = (const float*)d_in[1];
  const float* Wp = (const float*)d_in[8];
  const float* bp = (const float*)d_in[9];
  const float* Wo = (const float*)d_in[22];
  const float* bo = (const float*)d_in[23];

  const int n_user = in_sizes[0] / IN_DIM;
  const int n_post = in_sizes[1] / IN_DIM;
  const int n_max  = n_user > n_post ? n_user : n_post;
  const int E0 = in_sizes[2], E1 = in_sizes[4], E2 = in_sizes[6];
  const int ET = E0 + E1 + E2;
  const int n3 = n_user + n_user + n_post;
  float* out = (float*)d_out;

  // workspace layout (4-byte units; all segments multiple-of-4 floats -> float4 aligned)
  float* ws = (float*)d_ws;
  size_t off = 0;
  ushort_t* hu    = (ushort_t*)(ws + off); off += (size_t)n_user * HID / 2;
  ushort_t* hp    = (ushort_t*)(ws + off); off += (size_t)n_post * HID / 2;
  float* abuf     = ws + off; off += (size_t)6 * n_max * HEADS;
  float* wbuf     = ws + off; off += 6 * HH;
  ushort_t* aggA  = (ushort_t*)(ws + off); off += (size_t)n_max * HH / 2;
  ushort_t* aggB  = (ushort_t*)(ws + off); off += (size_t)n_max * HH / 2;
  ushort_t* aggC  = (ushort_t*)(ws + off); off += (size_t)n_max * HH / 2;
  ushort_t* Wt0   = (ushort_t*)(ws + off); off += 8192;
  ushort_t* Wt1   = (ushort_t*)(ws + off); off += 8192;
  ushort_t* Wt2   = (ushort_t*)(ws + off); off += 8192;
  ushort_t* Wot   = (ushort_t*)(ws + off); off += 8192;
  ushort_t* Wpt   = (ushort_t*)(ws + off); off += 4096;
  float* bsum_u   = ws + off; off += 256;
  int* deg3       = (int*)(ws + off); off += n3;
  int* offs3      = (int*)(ws + off); off += n3;
  int* cursor3    = (int*)(ws + off); off += n3;
  int* bsum       = (int*)(ws + off); off += 1024;
  int* csr_src    = (int*)(ws + off); off += ET;
  off = (off + 3) & ~(size_t)3;
  float4* alpha   = (float4*)(ws + off); off += (size_t)ET * 4;

  int n_total = n_user + n_post;

  prep_kernel<<<289, 256, 0, stream>>>(
      (const float*)d_in[10], (const float*)d_in[14], (const float*)d_in[18], Wo, Wp,
      (const float*)d_in[13], (const float*)d_in[17], Wt0, Wt1, Wt2, Wot, Wpt, bsum_u);

  proj_mfma<<<(n_total + 63) / 64, 256, 0, stream>>>(xu, xp, Wpt, bp, hu, hp, n_user, n_total);

  fold3_kernel<<<3, 256, 0, stream>>>(
      (const float*)d_in[10], (const float*)d_in[11], (const float*)d_in[12],
      (const float*)d_in[14], (const float*)d_in[15], (const float*)d_in[16],
      (const float*)d_in[18], (const float*)d_in[19], (const float*)d_in[20], wbuf);

  long waves6 = 4L * n_user + 2L * n_post;
  att6_kernel<<<(int)((waves6 + 3) / 4), 256, 0, stream>>>(hu, hp, wbuf, abuf, n_user, n_post, n_max);

  hipMemsetAsync(deg3, 0, (size_t)n3 * sizeof(int), stream);
  hist3_kernel<<<(ET + 255) / 256, 256, 0, stream>>>(
      (const int*)d_in[3], (const int*)d_in[5], (const int*)d_in[7],
      deg3, E0, E1, E2, n_user, 2 * n_user);
  int nb = (n3 + 255) / 256;
  scan1_kernel<<<nb, 256, 0, stream>>>(deg3, offs3, bsum, n3);
  scan2_kernel<<<1, 1024, 0, stream>>>(bsum, nb);
  scan3_kernel<<<nb, 256, 0, stream>>>(offs3, cursor3, bsum, n3);
  csrfill3_kernel<<<(ET + 255) / 256, 256, 0, stream>>>(
      (const int*)d_in[2], (const int*)d_in[3],
      (const int*)d_in[4], (const int*)d_in[5],
      (const int*)d_in[6], (const int*)d_in[7],
      cursor3, csr_src, E0, E1, E2, n_user, 2 * n_user);

  stats_alpha_kernel<<<(n3 + 255) / 256, 256, 0, stream>>>(
      csr_src, offs3, deg3, abuf, alpha, n_user, n_post, n_max);

  gather_slim<<<(n3 + 3) / 4, 256, 0, stream>>>(
      csr_src, offs3, deg3, hu, hp, alpha, n_user, n_post, aggA, aggB, aggC);

  user_epi_mfma<<<(n_user + 63) / 64, 256, 0, stream>>>(
      aggA, aggB, Wt0, Wt1, Wot, bsum_u, bo, out, n_user);

  post_epi_mfma<<<(n_post + 63) / 64, 256, 0, stream>>>(
      aggC, Wt2, (const float*)d_in[21], out + (size_t)n_user * OUT_DIM, n_post);
}

// Round 9
// 513.963 us; speedup vs baseline: 1.3398x; 1.3398x over previous
//
#include <hip/hip_runtime.h>
#include <math.h>

#define IN_DIM 128
#define HID 64
#define HEADS 4
#define HH 256   // HEADS*HID
#define OUT_DIM 64
#define NEG_SLOPE 0.2f

typedef unsigned short ushort_t;
using bf16x8 = __attribute__((ext_vector_type(8))) short;
using f32x4  = __attribute__((ext_vector_type(4))) float;

__device__ __forceinline__ float elu_f(float x){ return x > 0.f ? x : (expf(x) - 1.f); }
__device__ __forceinline__ float lrelu_f(float x){ return fmaxf(x, NEG_SLOPE * x); }

__device__ __forceinline__ ushort_t f2bf(float x){
  unsigned u = __float_as_uint(x);
  unsigned r = (u + 0x7fffu + ((u >> 16) & 1u)) >> 16;
  return (ushort_t)r;
}
__device__ __forceinline__ float bf2f(ushort_t v){ return __uint_as_float(((unsigned)v) << 16); }
__device__ __forceinline__ float bf2f_lo(unsigned v){ return __uint_as_float(v << 16); }
__device__ __forceinline__ float bf2f_hi(unsigned v){ return __uint_as_float(v & 0xffff0000u); }

// ---- prep: bf16 weights in MFMA B layout + transposed proj weight + summed user bias
__global__ void prep_kernel(const float* __restrict__ L0, const float* __restrict__ L1,
                            const float* __restrict__ L2, const float* __restrict__ Wo,
                            const float* __restrict__ Wp,
                            const float* __restrict__ b0, const float* __restrict__ b1,
                            ushort_t* __restrict__ Wt0, ushort_t* __restrict__ Wt1,
                            ushort_t* __restrict__ Wt2, ushort_t* __restrict__ Wot,
                            ushort_t* __restrict__ Wpt, float* __restrict__ bsum){
  int g = blockIdx.x * 256 + threadIdx.x;
  if (g < 49152){
    int m = g >> 14;
    int i = g & 16383;
    int h = i >> 12, rem = i & 4095;
    int o = rem >> 6, c = rem & 63;
    const float* L = m == 0 ? L0 : (m == 1 ? L1 : L2);
    ushort_t* W = m == 0 ? Wt0 : (m == 1 ? Wt1 : Wt2);
    W[i] = f2bf(L[(size_t)c * HH + h * 64 + o]);
  } else if (g < 65536){
    int i = g - 49152;
    int o = i >> 8, k = i & 255;
    Wot[i] = f2bf(Wo[(size_t)k * OUT_DIM + o]);
  } else if (g < 73728){
    int i = g - 65536;
    int c = i >> 7, k = i & 127;
    Wpt[i] = f2bf(Wp[(size_t)k * HID + c]);
  } else if (g < 73984){
    int i = g - 73728;
    bsum[i] = b0[i] + b1[i];
  }
}

// ---- proj via MFMA: h = x @ Wp + b, h stored bf16. 64 rows/block, 4 waves.
__global__ void proj_mfma(const float* __restrict__ xu, const float* __restrict__ xp,
                          const ushort_t* __restrict__ Wpt, const float* __restrict__ b,
                          ushort_t* __restrict__ hu, ushort_t* __restrict__ hp,
                          int n_user, int n_total){
  __shared__ ushort_t xs[64 * 128];   // 16 KB, byte ^= (row&7)<<4 swizzle
  int tid = threadIdx.x;
  int row0 = blockIdx.x * 64;
  #pragma unroll
  for (int p = 0; p < 4; ++p){
    int idx = (p * 256 + tid) * 8;
    int r = idx >> 7, k = idx & 127;
    int gr = row0 + r;
    float4 v0 = make_float4(0,0,0,0), v1 = make_float4(0,0,0,0);
    if (gr < n_total){
      const float* src = (gr < n_user) ? (xu + (size_t)gr * IN_DIM + k)
                                       : (xp + (size_t)(gr - n_user) * IN_DIM + k);
      v0 = *(const float4*)src; v1 = *(const float4*)(src + 4);
    }
    bf16x8 bv;
    bv[0] = (short)f2bf(v0.x); bv[1] = (short)f2bf(v0.y);
    bv[2] = (short)f2bf(v0.z); bv[3] = (short)f2bf(v0.w);
    bv[4] = (short)f2bf(v1.x); bv[5] = (short)f2bf(v1.y);
    bv[6] = (short)f2bf(v1.z); bv[7] = (short)f2bf(v1.w);
    int byteoff = r * 256 + ((k * 2) ^ ((r & 7) << 4));
    *(bf16x8*)((char*)xs + byteoff) = bv;
  }
  __syncthreads();
  int w = tid >> 6, lane = tid & 63, l15 = lane & 15, kg = lane >> 4;
  int arow = w * 16 + l15;
  bf16x8 afrag[4];
  #pragma unroll
  for (int ks = 0; ks < 4; ++ks){
    int k = ks * 32 + kg * 8;
    int byteoff = arow * 256 + ((k * 2) ^ ((arow & 7) << 4));
    afrag[ks] = *(const bf16x8*)((const char*)xs + byteoff);
  }
  #pragma unroll
  for (int n16 = 0; n16 < 4; ++n16){
    f32x4 acc = {0.f, 0.f, 0.f, 0.f};
    const ushort_t* wp = Wpt + (n16 * 16 + l15) * 128;
    #pragma unroll
    for (int ks = 0; ks < 4; ++ks)
      acc = __builtin_amdgcn_mfma_f32_16x16x32_bf16(afrag[ks], *(const bf16x8*)(wp + ks * 32 + kg * 8), acc, 0, 0, 0);
    int col = n16 * 16 + l15;
    float bb = b[col];
    #pragma unroll
    for (int j = 0; j < 4; ++j){
      int row = row0 + w * 16 + kg * 4 + j;
      if (row < n_total){
        ushort_t hv = f2bf(acc[j] + bb);
        if (row < n_user) hu[(size_t)row * HID + col] = hv;
        else              hp[(size_t)(row - n_user) * HID + col] = hv;
      }
    }
  }
}

// ---- batched fold: 3 blocks; wbuf layout: [t*2+0]=w_s, [t*2+1]=w_d (each 256)
__global__ void fold3_kernel(const float* __restrict__ lin0, const float* __restrict__ as0, const float* __restrict__ ad0,
                             const float* __restrict__ lin1, const float* __restrict__ as1, const float* __restrict__ ad1,
                             const float* __restrict__ lin2, const float* __restrict__ as2, const float* __restrict__ ad2,
                             float* __restrict__ wbuf){
  int t = blockIdx.x;
  const float* lin = t == 0 ? lin0 : (t == 1 ? lin1 : lin2);
  const float* as  = t == 0 ? as0  : (t == 1 ? as1  : as2);
  const float* ad  = t == 0 ? ad0  : (t == 1 ? ad1  : ad2);
  int tid = threadIdx.x;
  int h = tid >> 6, k = tid & 63;
  float vs = 0.f, vd = 0.f;
  for (int c = 0; c < HID; ++c){
    float lv = lin[k * HH + h * HID + c];
    vs += lv * as[h * HID + c];
    vd += lv * ad[h * HID + c];
  }
  wbuf[(t * 2 + 0) * HH + tid] = vs;
  wbuf[(t * 2 + 1) * HH + tid] = vd;
}

// ---- batched node attention: 6 segments; lane = (head, 4-channel group)
__global__ void att6_kernel(const ushort_t* __restrict__ hu, const ushort_t* __restrict__ hp,
                            const float* __restrict__ wbuf, float* __restrict__ abuf,
                            int n_user, int n_post, int n_max){
  long gw = ((long)blockIdx.x * blockDim.x + threadIdx.x) >> 6;
  int lane = threadIdx.x & 63;
  int seg, node;
  long r = gw;
  int nu = n_user, np_ = n_post;
  if      (r < nu)            { seg = 0; node = (int)r; }
  else if ((r -= nu) < nu)    { seg = 1; node = (int)r; }
  else if ((r -= nu) < np_)   { seg = 2; node = (int)r; }
  else if ((r -= np_) < nu)   { seg = 3; node = (int)r; }
  else if ((r -= nu) < nu)    { seg = 4; node = (int)r; }
  else if ((r -= nu) < np_)   { seg = 5; node = (int)r; }
  else return;
  const ushort_t* h = (seg == 2 || seg == 5) ? hp : hu;
  int hh = lane >> 4, cg = lane & 15;
  uint2 hr = *(const uint2*)(h + (size_t)node * HID + cg * 4);
  float c0 = bf2f_lo(hr.x), c1 = bf2f_hi(hr.x);
  float c2 = bf2f_lo(hr.y), c3 = bf2f_hi(hr.y);
  float4 wv = *(const float4*)(wbuf + seg * HH + hh * HID + cg * 4);
  float p = c0 * wv.x + c1 * wv.y + c2 * wv.z + c3 * wv.w;
  p += __shfl_xor(p, 1); p += __shfl_xor(p, 2);
  p += __shfl_xor(p, 4); p += __shfl_xor(p, 8);
  if (cg == 0) abuf[(size_t)seg * n_max * HEADS + (size_t)node * HEADS + hh] = p;
}

// ======== batched CSR build over 3 types ========
__global__ void hist3_kernel(const int* __restrict__ d0, const int* __restrict__ d1,
                             const int* __restrict__ d2, int* __restrict__ deg3,
                             int E0, int E1, int E2, int b1_, int b2_){
  int e = blockIdx.x * blockDim.x + threadIdx.x;
  int ET = E0 + E1 + E2;
  if (e >= ET) return;
  int idx;
  if (e < E0)            idx = d0[e];
  else if (e < E0 + E1)  idx = b1_ + d1[e - E0];
  else                   idx = b2_ + d2[e - E0 - E1];
  atomicAdd(deg3 + idx, 1);
}

__global__ void scan1_kernel(const int* __restrict__ deg, int* __restrict__ offs,
                             int* __restrict__ bsum, int n){
  __shared__ int sm[256];
  int i = blockIdx.x * 256 + threadIdx.x;
  int v = (i < n) ? deg[i] : 0;
  sm[threadIdx.x] = v;
  __syncthreads();
  for (int off = 1; off < 256; off <<= 1){
    int t = (threadIdx.x >= off) ? sm[threadIdx.x - off] : 0;
    __syncthreads();
    sm[threadIdx.x] += t;
    __syncthreads();
  }
  if (i < n) offs[i] = sm[threadIdx.x] - v;
  if (threadIdx.x == 255) bsum[blockIdx.x] = sm[255];
}

__global__ void scan2_kernel(int* __restrict__ bsum, int nb){
  __shared__ int sm[1024];
  int v = (threadIdx.x < nb) ? bsum[threadIdx.x] : 0;
  sm[threadIdx.x] = v;
  __syncthreads();
  for (int off = 1; off < 1024; off <<= 1){
    int t = (threadIdx.x >= off) ? sm[threadIdx.x - off] : 0;
    __syncthreads();
    sm[threadIdx.x] += t;
    __syncthreads();
  }
  if (threadIdx.x < nb) bsum[threadIdx.x] = sm[threadIdx.x] - v;
}

__global__ void scan3_kernel(int* __restrict__ offs, int* __restrict__ cursor,
                             const int* __restrict__ bsum, int n){
  int i = blockIdx.x * 256 + threadIdx.x;
  if (i >= n) return;
  int o = offs[i] + bsum[blockIdx.x];
  offs[i] = o;
  cursor[i] = o;
}

__global__ void csrfill3_kernel(const int* __restrict__ s0, const int* __restrict__ d0,
                                const int* __restrict__ s1, const int* __restrict__ d1,
                                const int* __restrict__ s2, const int* __restrict__ d2,
                                int* __restrict__ cursor, int* __restrict__ csr_src,
                                int E0, int E1, int E2, int b1_, int b2_){
  int e = blockIdx.x * blockDim.x + threadIdx.x;
  int ET = E0 + E1 + E2;
  if (e >= ET) return;
  int sidx, didx;
  if (e < E0){ sidx = s0[e]; didx = d0[e]; }
  else if (e < E0 + E1){ int ee = e - E0; sidx = s1[ee]; didx = b1_ + d1[ee]; }
  else { int ee = e - E0 - E1; sidx = s2[ee]; didx = b2_ + d2[ee]; }
  int pos = atomicAdd(cursor + didx, 1);
  csr_src[pos] = sidx;
}

// ---- fused gather: wave per dst = 4 edge-slots x 16 channel-lanes.
// alpha computed inline (softmax without max-sub, validated r6-r8);
// 4 edges in flight -> 4x MLP vs serial; butterfly-reduce over slots.
__global__ void gather_fused(const int* __restrict__ csr_src, const int* __restrict__ offs3,
                             const int* __restrict__ deg3,
                             const ushort_t* __restrict__ hu, const ushort_t* __restrict__ hp,
                             const float* __restrict__ abuf,
                             int n_user, int n_post, int n_max,
                             ushort_t* __restrict__ aggA, ushort_t* __restrict__ aggB,
                             ushort_t* __restrict__ aggC){
  int gw = blockIdx.x * 4 + (threadIdx.x >> 6);
  int lane = threadIdx.x & 63;
  int es = lane >> 4;          // edge slot 0..3
  int cg = lane & 15;          // channel group (4 channels)
  int n3 = 2 * n_user + n_post;
  if (gw >= n3) return;
  const ushort_t* h; ushort_t* agg; int dloc;
  size_t astr = (size_t)n_max;   // float4 units
  const float4* ab = (const float4*)abuf;
  const float4* as4; const float4* ad4;
  if (gw < n_user){ dloc = gw; h = hu; agg = aggA; as4 = ab; ad4 = ab + astr; }
  else if (gw < 2 * n_user){ dloc = gw - n_user; h = hp; agg = aggB; as4 = ab + 2 * astr; ad4 = ab + 3 * astr; }
  else { dloc = gw - 2 * n_user; h = hu; agg = aggC; as4 = ab + 4 * astr; ad4 = ab + 5 * astr; }
  int base = offs3[gw], n = deg3[gw];
  float4 ad = ad4[dloc];

  float acc[HEADS][4];
  #pragma unroll
  for (int a = 0; a < HEADS; ++a)
    #pragma unroll
    for (int c = 0; c < 4; ++c) acc[a][c] = 0.f;
  float ssum[HEADS] = {0.f, 0.f, 0.f, 0.f};

  if (n > 0){
    // depth-2 pipeline over 4-edge batches
    int j = es;
    int jc = j < n ? j : n - 1;
    bool v = j < n;
    int src = csr_src[base + jc];
    uint2 hr = *(const uint2*)(h + (size_t)src * HID + cg * 4);
    float4 av = as4[src];
    for (int j0 = 0; j0 < n; j0 += 4){
      uint2 hr_c = hr; float4 av_c = av; bool v_c = v;
      int jn = j0 + 4 + es;
      if (j0 + 4 < n){
        int jcn = jn < n ? jn : n - 1;
        v = jn < n;
        int srcn = csr_src[base + jcn];
        hr = *(const uint2*)(h + (size_t)srcn * HID + cg * 4);
        av = as4[srcn];
      }
      float p0 = v_c ? __expf(lrelu_f(av_c.x + ad.x)) : 0.f;
      float p1 = v_c ? __expf(lrelu_f(av_c.y + ad.y)) : 0.f;
      float p2 = v_c ? __expf(lrelu_f(av_c.z + ad.z)) : 0.f;
      float p3 = v_c ? __expf(lrelu_f(av_c.w + ad.w)) : 0.f;
      float c0 = bf2f_lo(hr_c.x), c1 = bf2f_hi(hr_c.x);
      float c2 = bf2f_lo(hr_c.y), c3 = bf2f_hi(hr_c.y);
      ssum[0] += p0; ssum[1] += p1; ssum[2] += p2; ssum[3] += p3;
      acc[0][0] = fmaf(p0, c0, acc[0][0]); acc[0][1] = fmaf(p0, c1, acc[0][1]);
      acc[0][2] = fmaf(p0, c2, acc[0][2]); acc[0][3] = fmaf(p0, c3, acc[0][3]);
      acc[1][0] = fmaf(p1, c0, acc[1][0]); acc[1][1] = fmaf(p1, c1, acc[1][1]);
      acc[1][2] = fmaf(p1, c2, acc[1][2]); acc[1][3] = fmaf(p1, c3, acc[1][3]);
      acc[2][0] = fmaf(p2, c0, acc[2][0]); acc[2][1] = fmaf(p2, c1, acc[2][1]);
      acc[2][2] = fmaf(p2, c2, acc[2][2]); acc[2][3] = fmaf(p2, c3, acc[2][3]);
      acc[3][0] = fmaf(p3, c0, acc[3][0]); acc[3][1] = fmaf(p3, c1, acc[3][1]);
      acc[3][2] = fmaf(p3, c2, acc[3][2]); acc[3][3] = fmaf(p3, c3, acc[3][3]);
    }
  }
  // reduce across the 4 edge slots (lane bits 4,5)
  #pragma unroll
  for (int a = 0; a < HEADS; ++a){
    ssum[a] += __shfl_xor(ssum[a], 16);
    ssum[a] += __shfl_xor(ssum[a], 32);
    #pragma unroll
    for (int c = 0; c < 4; ++c){
      acc[a][c] += __shfl_xor(acc[a][c], 16);
      acc[a][c] += __shfl_xor(acc[a][c], 32);
    }
  }
  if (es == 0){
    #pragma unroll
    for (int a = 0; a < HEADS; ++a){
      float inv = 1.f / (ssum[a] + 1e-16f);
      unsigned w0 = (unsigned)f2bf(acc[a][0] * inv) | ((unsigned)f2bf(acc[a][1] * inv) << 16);
      unsigned w1 = (unsigned)f2bf(acc[a][2] * inv) | ((unsigned)f2bf(acc[a][3] * inv) << 16);
      *(uint2*)(agg + (size_t)dloc * HH + a * HID + cg * 4) = make_uint2(w0, w1);
    }
  }
}

// ---- user epilogue (MFMA): out_user = elu(aggA@L0 + aggB@L1 + bsum) @ Wo + bo
__global__ void user_epi_mfma(const ushort_t* __restrict__ aggA, const ushort_t* __restrict__ aggB,
                              const ushort_t* __restrict__ Wt0, const ushort_t* __restrict__ Wt1,
                              const ushort_t* __restrict__ Wot, const float* __restrict__ bsum,
                              const float* __restrict__ bo, float* __restrict__ out, int n){
  __shared__ ushort_t Tl[64 * 256];   // 32 KB, swizzled: byte ^= (row&7)<<4
  int tid = threadIdx.x;
  int w = tid >> 6, lane = tid & 63;
  int l15 = lane & 15, kg = lane >> 4;
  int row0 = blockIdx.x * 64 + w * 16;

  int ar = row0 + l15; if (ar > n - 1) ar = n - 1;
  #pragma unroll
  for (int h = 0; h < HEADS; ++h){
    const ushort_t* pa = aggA + (size_t)ar * HH + h * 64 + kg * 8;
    const ushort_t* pb = aggB + (size_t)ar * HH + h * 64 + kg * 8;
    bf16x8 aA0 = *(const bf16x8*)pa;
    bf16x8 aA1 = *(const bf16x8*)(pa + 32);
    bf16x8 aB0 = *(const bf16x8*)pb;
    bf16x8 aB1 = *(const bf16x8*)(pb + 32);
    #pragma unroll
    for (int n16 = 0; n16 < 4; ++n16){
      int o = n16 * 16 + l15;
      const ushort_t* w0 = Wt0 + h * 4096 + o * 64 + kg * 8;
      const ushort_t* w1 = Wt1 + h * 4096 + o * 64 + kg * 8;
      f32x4 acc = {0.f, 0.f, 0.f, 0.f};
      acc = __builtin_amdgcn_mfma_f32_16x16x32_bf16(aA0, *(const bf16x8*)w0, acc, 0, 0, 0);
      acc = __builtin_amdgcn_mfma_f32_16x16x32_bf16(aA1, *(const bf16x8*)(w0 + 32), acc, 0, 0, 0);
      acc = __builtin_amdgcn_mfma_f32_16x16x32_bf16(aB0, *(const bf16x8*)w1, acc, 0, 0, 0);
      acc = __builtin_amdgcn_mfma_f32_16x16x32_bf16(aB1, *(const bf16x8*)(w1 + 32), acc, 0, 0, 0);
      int col = h * 64 + n16 * 16 + l15;
      float bb = bsum[col];
      #pragma unroll
      for (int j = 0; j < 4; ++j){
        int rl = w * 16 + kg * 4 + j;
        float v = elu_f(acc[j] + bb);
        int byteoff = rl * 512 + ((col * 2) ^ ((rl & 7) << 4));
        Tl[byteoff >> 1] = f2bf(v);
      }
    }
  }
  __syncthreads();

  int rl = w * 16 + l15;
  #pragma unroll
  for (int nf = 0; nf < 4; ++nf){
    f32x4 acc = {0.f, 0.f, 0.f, 0.f};
    const ushort_t* wp = Wot + (nf * 16 + l15) * 256 + kg * 8;
    #pragma unroll
    for (int ks = 0; ks < 8; ++ks){
      int ab = rl * 512 + ((ks * 64 + kg * 16) ^ ((rl & 7) << 4));
      bf16x8 a = *(const bf16x8*)((const char*)Tl + ab);
      acc = __builtin_amdgcn_mfma_f32_16x16x32_bf16(a, *(const bf16x8*)(wp + ks * 32), acc, 0, 0, 0);
    }
    int colo = nf * 16 + l15;
    float bb = bo[colo];
    #pragma unroll
    for (int j = 0; j < 4; ++j){
      int row = blockIdx.x * 64 + w * 16 + kg * 4 + j;
      if (row < n) out[(size_t)row * OUT_DIM + colo] = acc[j] + bb;
    }
  }
}

// ---- post epilogue (MFMA): out_post = elu(aggC@L2 + b2)
__global__ void post_epi_mfma(const ushort_t* __restrict__ aggC, const ushort_t* __restrict__ Wt2,
                              const float* __restrict__ b2, float* __restrict__ out, int n){
  int tid = threadIdx.x;
  int w = tid >> 6, lane = tid & 63;
  int l15 = lane & 15, kg = lane >> 4;
  int row0 = blockIdx.x * 64 + w * 16;
  int ar = row0 + l15; if (ar > n - 1) ar = n - 1;
  #pragma unroll
  for (int h = 0; h < HEADS; ++h){
    const ushort_t* pa = aggC + (size_t)ar * HH + h * 64 + kg * 8;
    bf16x8 a0 = *(const bf16x8*)pa;
    bf16x8 a1 = *(const bf16x8*)(pa + 32);
    #pragma unroll
    for (int n16 = 0; n16 < 4; ++n16){
      int o = n16 * 16 + l15;
      const ushort_t* w2 = Wt2 + h * 4096 + o * 64 + kg * 8;
      f32x4 acc = {0.f, 0.f, 0.f, 0.f};
      acc = __builtin_amdgcn_mfma_f32_16x16x32_bf16(a0, *(const bf16x8*)w2, acc, 0, 0, 0);
      acc = __builtin_amdgcn_mfma_f32_16x16x32_bf16(a1, *(const bf16x8*)(w2 + 32), acc, 0, 0, 0);
      int col = h * 64 + n16 * 16 + l15;
      float bb = b2[col];
      #pragma unroll
      for (int j = 0; j < 4; ++j){
        int row = row0 + kg * 4 + j;
        if (row < n) out[(size_t)row * HH + col] = elu_f(acc[j] + bb);
      }
    }
  }
}

extern "C" void kernel_launch(void* const* d_in, const int* in_sizes, int n_in,
                              void* d_out, int out_size, void* d_ws, size_t ws_size,
                              hipStream_t stream){
  const float* xu = (const float*)d_in[0];
  const float* xp = (const float*)d_in[1];
  const float* Wp = (const float*)d_in[8];
  const float* bp = (const float*)d_in[9];
  const float* Wo = (const float*)d_in[22];
  const float* bo = (const float*)d_in[23];

  const int n_user = in_sizes[0] / IN_DIM;
  const int n_post = in_sizes[1] / IN_DIM;
  const int n_max  = n_user > n_post ? n_user : n_post;
  const int E0 = in_sizes[2], E1 = in_sizes[4], E2 = in_sizes[6];
  const int ET = E0 + E1 + E2;
  const int n3 = n_user + n_user + n_post;
  float* out = (float*)d_out;

  // workspace layout (4-byte units)
  float* ws = (float*)d_ws;
  size_t off = 0;
  ushort_t* hu    = (ushort_t*)(ws + off); off += (size_t)n_user * HID / 2;
  ushort_t* hp    = (ushort_t*)(ws + off); off += (size_t)n_post * HID / 2;
  float* abuf     = ws + off; off += (size_t)6 * n_max * HEADS;
  float* wbuf     = ws + off; off += 6 * HH;
  ushort_t* aggA  = (ushort_t*)(ws + off); off += (size_t)n_max * HH / 2;
  ushort_t* aggB  = (ushort_t*)(ws + off); off += (size_t)n_max * HH / 2;
  ushort_t* aggC  = (ushort_t*)(ws + off); off += (size_t)n_max * HH / 2;
  ushort_t* Wt0   = (ushort_t*)(ws + off); off += 8192;
  ushort_t* Wt1   = (ushort_t*)(ws + off); off += 8192;
  ushort_t* Wt2   = (ushort_t*)(ws + off); off += 8192;
  ushort_t* Wot   = (ushort_t*)(ws + off); off += 8192;
  ushort_t* Wpt   = (ushort_t*)(ws + off); off += 4096;
  float* bsum_u   = ws + off; off += 256;
  int* deg3       = (int*)(ws + off); off += n3;
  int* offs3      = (int*)(ws + off); off += n3;
  int* cursor3    = (int*)(ws + off); off += n3;
  int* bsum       = (int*)(ws + off); off += 1024;
  int* csr_src    = (int*)(ws + off); off += ET;

  int n_total = n_user + n_post;

  prep_kernel<<<289, 256, 0, stream>>>(
      (const float*)d_in[10], (const float*)d_in[14], (const float*)d_in[18], Wo, Wp,
      (const float*)d_in[13], (const float*)d_in[17], Wt0, Wt1, Wt2, Wot, Wpt, bsum_u);

  proj_mfma<<<(n_total + 63) / 64, 256, 0, stream>>>(xu, xp, Wpt, bp, hu, hp, n_user, n_total);

  fold3_kernel<<<3, 256, 0, stream>>>(
      (const float*)d_in[10], (const float*)d_in[11], (const float*)d_in[12],
      (const float*)d_in[14], (const float*)d_in[15], (const float*)d_in[16],
      (const float*)d_in[18], (const float*)d_in[19], (const float*)d_in[20], wbuf);

  long waves6 = 4L * n_user + 2L * n_post;
  att6_kernel<<<(int)((waves6 + 3) / 4), 256, 0, stream>>>(hu, hp, wbuf, abuf, n_user, n_post, n_max);

  hipMemsetAsync(deg3, 0, (size_t)n3 * sizeof(int), stream);
  hist3_kernel<<<(ET + 255) / 256, 256, 0, stream>>>(
      (const int*)d_in[3], (const int*)d_in[5], (const int*)d_in[7],
      deg3, E0, E1, E2, n_user, 2 * n_user);
  int nb = (n3 + 255) / 256;
  scan1_kernel<<<nb, 256, 0, stream>>>(deg3, offs3, bsum, n3);
  scan2_kernel<<<1, 1024, 0, stream>>>(bsum, nb);
  scan3_kernel<<<nb, 256, 0, stream>>>(offs3, cursor3, bsum, n3);
  csrfill3_kernel<<<(ET + 255) / 256, 256, 0, stream>>>(
      (const int*)d_in[2], (const int*)d_in[3],
      (const int*)d_in[4], (const int*)d_in[5],
      (const int*)d_in[6], (const int*)d_in[7],
      cursor3, csr_src, E0, E1, E2, n_user, 2 * n_user);

  gather_fused<<<(n3 + 3) / 4, 256, 0, stream>>>(
      csr_src, offs3, deg3, hu, hp, abuf, n_user, n_post, n_max, aggA, aggB, aggC);

  user_epi_mfma<<<(n_user + 63) / 64, 256, 0, stream>>>(
      aggA, aggB, Wt0, Wt1, Wot, bsum_u, bo, out, n_user);

  post_epi_mfma<<<(n_post + 63) / 64, 256, 0, stream>>>(
      aggC, Wt2, (const float*)d_in[21], out + (size_t)n_user * OUT_DIM, n_post);
}